// Round 15
// baseline (112.287 us; speedup 1.0000x reference)
//
#include <hip/hip_runtime.h>

typedef unsigned char u8;
typedef unsigned short u16;
typedef unsigned int u32;
typedef unsigned long long u64;
typedef long long i64;
typedef __attribute__((ext_vector_type(16))) float floatx16;
typedef __attribute__((ext_vector_type(4))) int intx4;
typedef __attribute__((ext_vector_type(8))) int intx8;

#define BN 8192
#define DIM 256
#define NSPLIT 8
#define KPS (BN / NSPLIT)   // 1024 keys per split
#define BKN 64              // keys per barrier period (2 x 32-key QK subtiles)
#define NIT (KPS / BKN)     // 16 iters
#define L2E 1.44269504f     // log2(e)

__device__ __forceinline__ u16 f2bf(float x) {
    u32 u = __builtin_bit_cast(u32, x);
    u = (u + 0x7fffu + ((u >> 16) & 1u)) >> 16;
    return (u16)u;
}
__device__ __forceinline__ float bf2f(u16 h) {
    return __builtin_bit_cast(float, (u32)h << 16);
}
__device__ __forceinline__ u64 pack4bf(float a, float b, float c, float d) {
    return (u64)f2bf(a) | ((u64)f2bf(b) << 16) | ((u64)f2bf(c) << 32) | ((u64)f2bf(d) << 48);
}
__device__ __forceinline__ u32 pk_fp8(float a, float b, float c, float d) {
    int v = __builtin_amdgcn_cvt_pk_fp8_f32(a, b, 0, false);
    v = __builtin_amdgcn_cvt_pk_fp8_f32(c, d, v, true);
    return (u32)v;
}
__device__ __forceinline__ void gl_lds16(const void* g, void* l) {
    __builtin_amdgcn_global_load_lds(
        (const __attribute__((address_space(1))) u32*)g,
        (__attribute__((address_space(3))) u32*)l, 16, 0, 0);
}
// bare v_exp_f32 (2^x): R13 lesson — libm exp2f lowers to the OCML precise
// multi-instruction path (VALU ballooned 16->23us); the builtin is 1 instr.
__device__ __forceinline__ float ex2(float x) { return __builtin_amdgcn_exp2f(x); }
// v_permlane32_swap_b32 a, b: a' = [a.lo, b.lo], b' = [a.hi, b.hi]
__device__ __forceinline__ void plswap(u32& a, u32& b) {
    asm("v_permlane32_swap_b32 %0, %1" : "+v"(a), "+v"(b));
}
// MX-scaled fp8 MFMA, K=64, unit scales (e8m0 0x7F = 2^0): runs at the MX rate
// (4686 TF ubench = 2.13x the non-scaled fp8 rate). R18/R19 verified both sides.
#define MFMA64S(A, B, C) __builtin_amdgcn_mfma_scale_f32_32x32x64_f8f6f4( \
        (A), (B), (C), 0, 0, 0, (int)0x7f7f7f7f, 0, (int)0x7f7f7f7f)

// ---------------- kernel 1: row l2-norm -> fp8 fb (K image) + fbq (log2e-scaled Q image)
// + fp8 fv (V^T tile images) ----
__global__ __launch_bounds__(256) void k_prep(const float* __restrict__ in,
                                              u8* __restrict__ fb, u8* __restrict__ fbq,
                                              u8* __restrict__ fv) {
    __shared__ u16 t[32 * 260];
    const int tid = threadIdx.x;
    const int wave = tid >> 6, lane = tid & 63;
    const int kb = blockIdx.x, r0 = kb * 32;
    #pragma unroll
    for (int i = 0; i < 8; ++i) {
        const int rl = wave * 8 + i;
        const float4 v = *(const float4*)(in + (size_t)(r0 + rl) * DIM + lane * 4);
        float ss = v.x * v.x + v.y * v.y + v.z * v.z + v.w * v.w;
        #pragma unroll
        for (int off = 1; off < 64; off <<= 1) ss += __shfl_xor(ss, off, 64);
        const float inv = 1.0f / fmaxf(sqrtf(ss), 1e-12f);
        const float n0 = v.x * inv, n1 = v.y * inv, n2 = v.z * inv, n3 = v.w * inv;
        *(u32*)(fb + (size_t)(r0 + rl) * DIM + lane * 4) = pk_fp8(n0, n1, n2, n3);
        // Q image pre-scaled by log2e: exp(q.k) = 2^((L2E q).k) -> bare v_exp_f32 in flash
        *(u32*)(fbq + (size_t)(r0 + rl) * DIM + lane * 4) =
            pk_fp8(n0 * L2E, n1 * L2E, n2 * L2E, n3 * L2E);
        *(u64*)(&t[rl * 260 + lane * 4]) = pack4bf(n0, n1, n2, n3);
    }
    __syncthreads();
    #pragma unroll
    for (int i = 0; i < 4; ++i) {
        const int S = i * 256 + tid;              // 8-byte slot index 0..1023
        const int d = S >> 2;
        const int c = ((S & 3) - (d >> 2)) & 3;   // key octet
        float f[8];
        #pragma unroll
        for (int j = 0; j < 8; ++j) f[j] = bf2f(t[(8 * c + j) * 260 + d]);
        const u32 lo = pk_fp8(f[0], f[1], f[2], f[3]);
        const u32 hi = pk_fp8(f[4], f[5], f[6], f[7]);
        *(u64*)(fv + (size_t)kb * 8192 + S * 8) = ((u64)hi << 32) | lo;
    }
}

// ---------------- kernel 2: fp8 flash attention, K=64 MX path for QK AND PV ----------------
// R23 = R22 with ONE change: de-phase sleep 24 -> 50 (~3200 cyc).
// R22 confirmed the bare-v_exp fix (flash ~44us, session-best total 111.6).
// The sleep was sized at ~1/4 iter from a stale estimate; measured iter period
// is now flash 44us/16 = ~6450 cyc, so anti-phase (max MFMA<->VALU overlap
// between the 2 co-resident blocks) wants ~3200 cyc = s_sleep(50).
// Pre-committed read: <1us delta => de-phase saturated, line closed.
__global__ __launch_bounds__(256, 2) void k_flash(
        const u8* __restrict__ fb, const u8* __restrict__ fbq, const u8* __restrict__ fv,
        u16* __restrict__ Opart, float* __restrict__ lpart) {
    __shared__ u8 tileK[2][16384];  // key-major fp8, chunk-swizzled, 2x32-key subtiles
    __shared__ u8 tileV[2][16384];  // pre-swizzled V^T fp8 images, 2x8KB subtiles

    const int tid = threadIdx.x;
    const int wave = tid >> 6, lane = tid & 63;
    const int c31 = lane & 31, g1 = lane >> 5;
    const int split = blockIdx.x & (NSPLIT - 1);
    const int qblk = blockIdx.x >> 3;
    const int q0 = qblk * 128 + wave * 32;
    const int key0 = split * KPS;

    // Q B-frags for K=64 MFMA (R18-verified layout), from the log2e-scaled image
    intx8 qf[4];
    #pragma unroll
    for (int g = 0; g < 4; ++g) {
        const u8* qb = fbq + (size_t)(q0 + c31) * DIM + g * 64 + g1 * 32;
        const intx4 lo = *(const intx4*)(qb);
        const intx4 hi = *(const intx4*)(qb + 16);
        qf[g] = __builtin_shufflevector(lo, hi, 0, 1, 2, 3, 4, 5, 6, 7);
    }

    floatx16 o[8];
    #pragma unroll
    for (int i = 0; i < 8; ++i)
        #pragma unroll
        for (int r = 0; r < 16; ++r) o[i][r] = 0.f;
    float lsum = 0.f;

    int offK[4];
    #pragma unroll
    for (int i = 0; i < 4; ++i) {
        const int S = wave * 256 + i * 64 + lane;   // 16B slot 0..1023 (64 key rows)
        const int r = S >> 4, s = S & 15;
        const int c = (s & 8) | ((s ^ r) & 7);
        offK[i] = r * 256 + c * 16;
    }
    const u8* gK = fb + (size_t)key0 * DIM;
    const u8* gV = fv + (size_t)(key0 >> 5) * 8192;

    auto stage = [&](int s, int b) {
        const size_t oo = (size_t)s * 16384;
        u8* lK = &tileK[b][0];
        u8* lV = &tileV[b][0] + wave * 4096;
        #pragma unroll
        for (int i = 0; i < 4; ++i)
            gl_lds16(gK + oo + offK[i], lK + wave * 4096 + i * 1024);
        #pragma unroll
        for (int i = 0; i < 4; ++i)
            gl_lds16(gV + oo + wave * 4096 + i * 1024 + lane * 16, lV + i * 1024);
    };

    // V chunk rotation offsets: piece p lives at chunk (p + (c31>>2)) & 3
    const int rot = c31 >> 2;
    const int co0 = ((rot) & 3) * 8, co1 = ((1 + rot) & 3) * 8;
    const int co2 = ((2 + rot) & 3) * 8, co3 = ((3 + rot) & 3) * 8;

    stage(0, 0);
    // de-phase the co-resident pair: bit 8 flips between block i and i+256.
    // s_sleep(50) ~ 3200 cyc ~ half the measured 6450-cyc iter period (anti-phase).
    if ((blockIdx.x >> 8) & 1) __builtin_amdgcn_s_sleep(50);

    for (int it = 0; it < NIT; ++it) {
        const int b = it & 1;
        __syncthreads();                   // drains DMA(it), issued one iter ago
        if (it + 1 < NIT) stage(it + 1, b ^ 1);

        const u8* tk = &tileK[b][0];
        const u8* bk0 = tk + c31 * 256;            // K subtile 0 (keys 0..31)
        const u8* bk1 = tk + 8192 + c31 * 256;     // K subtile 1 (keys 32..63)
        const u8* vbase = &tileV[b][0] + g1 * 8192 + c31 * 32;

        // K A-frag loader (R18-verified): k-group g from subtile base bk
        auto ldk = [&](const u8* bk, int g) -> intx8 {
            const int cw = g * 4 + g1 * 2;
            const int sl = (cw & 8) | ((cw ^ c31) & 7);
            const intx4 lo = *(const intx4*)(bk + sl * 16);
            const intx4 hi = *(const intx4*)(bk + (sl ^ 1) * 16);
            return __builtin_shufflevector(lo, hi, 0, 1, 2, 3, 4, 5, 6, 7);
        };
        // V B-frag loader: d-block ds, 4 rotated 8B pieces -> 8 u32 words
        auto ldv = [&](int ds) -> intx8 {
            const u8* vb = vbase + ds * 1024;
            const i64 v0 = *(const i64*)(vb + co0);
            const i64 v1 = *(const i64*)(vb + co1);
            const i64 v2 = *(const i64*)(vb + co2);
            const i64 v3 = *(const i64*)(vb + co3);
            intx8 r;
            r[0] = (int)v0; r[1] = (int)(v0 >> 32);
            r[2] = (int)v1; r[3] = (int)(v1 >> 32);
            r[4] = (int)v2; r[5] = (int)(v2 >> 32);
            r[6] = (int)v3; r[7] = (int)(v3 >> 32);
            return r;
        };

        floatx16 s0, s1;
        #pragma unroll
        for (int r = 0; r < 16; ++r) { s0[r] = 0.f; s1[r] = 0.f; }

        // ---- QK subtile 0 (keys 0..31), k-frag loads interleaved ----
        intx8 ka0 = ldk(bk0, 0);
        intx8 ka1 = ldk(bk0, 1);
        __builtin_amdgcn_s_setprio(1);
        s0 = MFMA64S(ka0, qf[0], s0); ka0 = ldk(bk0, 2);
        s0 = MFMA64S(ka1, qf[1], s0); ka1 = ldk(bk0, 3);
        s0 = MFMA64S(ka0, qf[2], s0); ka0 = ldk(bk1, 0);
        s0 = MFMA64S(ka1, qf[3], s0); ka1 = ldk(bk1, 1);
        __builtin_amdgcn_s_setprio(0);

        // ---- QK subtile 1 (keys 32..63), exp2(s0) interleaved ----
        __builtin_amdgcn_s_setprio(1);
        s1 = MFMA64S(ka0, qf[0], s1);
        const float f00 = ex2(s0[0]), f01 = ex2(s0[1]), f02 = ex2(s0[2]), f03 = ex2(s0[3]);
        const float f04 = ex2(s0[4]), f05 = ex2(s0[5]), f06 = ex2(s0[6]), f07 = ex2(s0[7]);
        ka0 = ldk(bk1, 2);
        s1 = MFMA64S(ka1, qf[1], s1);
        const float f08 = ex2(s0[8]), f09 = ex2(s0[9]), f10 = ex2(s0[10]), f11 = ex2(s0[11]);
        const float f12 = ex2(s0[12]), f13 = ex2(s0[13]), f14 = ex2(s0[14]), f15 = ex2(s0[15]);
        ka1 = ldk(bk1, 3);
        s1 = MFMA64S(ka0, qf[2], s1);
        const u32 pA0 = pk_fp8(f00, f01, f02, f03);
        const u32 pA1 = pk_fp8(f04, f05, f06, f07);
        const u32 pA2 = pk_fp8(f08, f09, f10, f11);
        const u32 pA3 = pk_fp8(f12, f13, f14, f15);
        lsum += ((f00 + f01) + (f02 + f03)) + ((f04 + f05) + (f06 + f07));
        lsum += ((f08 + f09) + (f10 + f11)) + ((f12 + f13) + (f14 + f15));
        s1 = MFMA64S(ka1, qf[3], s1);
        __builtin_amdgcn_s_setprio(0);

        // ---- exp2(s1) -> p(1); assemble K=64 P A-frag via permlane32_swap ----
        const float g00 = ex2(s1[0]), g01 = ex2(s1[1]), g02 = ex2(s1[2]), g03 = ex2(s1[3]);
        const float g04 = ex2(s1[4]), g05 = ex2(s1[5]), g06 = ex2(s1[6]), g07 = ex2(s1[7]);
        const float g08 = ex2(s1[8]), g09 = ex2(s1[9]), g10 = ex2(s1[10]), g11 = ex2(s1[11]);
        const float g12 = ex2(s1[12]), g13 = ex2(s1[13]), g14 = ex2(s1[14]), g15 = ex2(s1[15]);
        u32 w0 = pA0, w1 = pk_fp8(g00, g01, g02, g03);
        u32 w2 = pA1, w3 = pk_fp8(g04, g05, g06, g07);
        u32 w4 = pA2, w5 = pk_fp8(g08, g09, g10, g11);
        u32 w6 = pA3, w7 = pk_fp8(g12, g13, g14, g15);
        lsum += ((g00 + g01) + (g02 + g03)) + ((g04 + g05) + (g06 + g07));
        lsum += ((g08 + g09) + (g10 + g11)) + ((g12 + g13) + (g14 + g15));
        plswap(w0, w1);   // w0 = PA[0] = [pA.lo, pB.lo]; w1 = PA[1] = [pA.hi, pB.hi]
        plswap(w2, w3);
        plswap(w4, w5);
        plswap(w6, w7);
        intx8 PA;
        PA[0] = (int)w0; PA[1] = (int)w1;
        PA[2] = (int)w2; PA[3] = (int)w3;
        PA[4] = (int)w4; PA[5] = (int)w5;
        PA[6] = (int)w6; PA[7] = (int)w7;

        // ---- PV: 8 x K=64 MFMAs, V-frag loads pipelined 2 deep ----
        intx8 v0 = ldv(0), v1 = ldv(1);
        __builtin_amdgcn_s_setprio(1);
        o[0] = MFMA64S(PA, v0, o[0]); v0 = ldv(2);
        o[1] = MFMA64S(PA, v1, o[1]); v1 = ldv(3);
        o[2] = MFMA64S(PA, v0, o[2]); v0 = ldv(4);
        o[3] = MFMA64S(PA, v1, o[3]); v1 = ldv(5);
        o[4] = MFMA64S(PA, v0, o[4]); v0 = ldv(6);
        o[5] = MFMA64S(PA, v1, o[5]); v1 = ldv(7);
        o[6] = MFMA64S(PA, v0, o[6]);
        o[7] = MFMA64S(PA, v1, o[7]);
        __builtin_amdgcn_s_setprio(0);
    }

    // ---- epilogue: bf16 partial O + fp32 partial l ----
    u16* ob = Opart + ((size_t)split * BN + q0) * DIM;
    #pragma unroll
    for (int ds = 0; ds < 8; ++ds) {
        #pragma unroll
        for (int r = 0; r < 16; ++r) {
            const int ql = (r & 3) + 8 * (r >> 2) + 4 * g1;
            ob[(size_t)ql * DIM + ds * 32 + c31] = f2bf(o[ds][r]);
        }
    }
    lsum += __shfl_xor(lsum, 32, 64);
    if (g1 == 0) lpart[(size_t)split * BN + q0 + c31] = lsum;
}

// ---------------- kernel 3: merge splits, blend, final l2-normalize ----------------
__global__ __launch_bounds__(256) void k_combine(
        const float* __restrict__ feats, const u16* __restrict__ Opart,
        const float* __restrict__ lpart, float* __restrict__ out) {
    const int row = blockIdx.x * 4 + (threadIdx.x >> 6);
    const int lane = threadIdx.x & 63;

    float L = 0.f;
    #pragma unroll
    for (int s = 0; s < NSPLIT; ++s) L += lpart[(size_t)s * BN + row];

    float a0 = 0.f, a1 = 0.f, a2 = 0.f, a3 = 0.f;
    #pragma unroll
    for (int s = 0; s < NSPLIT; ++s) {
        const ushort4 o = *(const ushort4*)(Opart + ((size_t)s * BN + row) * DIM + lane * 4);
        a0 += bf2f(o.x); a1 += bf2f(o.y); a2 += bf2f(o.z); a3 += bf2f(o.w);
    }
    const float invL = 1.0f / L;

    const float4 v = *(const float4*)(feats + (size_t)row * DIM + lane * 4);
    float ss = v.x * v.x + v.y * v.y + v.z * v.z + v.w * v.w;
    #pragma unroll
    for (int off = 1; off < 64; off <<= 1) ss += __shfl_xor(ss, off, 64);
    const float invf = 1.0f / fmaxf(sqrtf(ss), 1e-12f);

    const float yx = 0.8f * v.x * invf + 0.2f * a0 * invL;
    const float yy = 0.8f * v.y * invf + 0.2f * a1 * invL;
    const float yz = 0.8f * v.z * invf + 0.2f * a2 * invL;
    const float yw = 0.8f * v.w * invf + 0.2f * a3 * invL;

    float s2 = yx * yx + yy * yy + yz * yz + yw * yw;
    #pragma unroll
    for (int off = 1; off < 64; off <<= 1) s2 += __shfl_xor(s2, off, 64);
    const float invn = 1.0f / fmaxf(sqrtf(s2), 1e-12f);

    float4 o; o.x = yx * invn; o.y = yy * invn; o.z = yz * invn; o.w = yw * invn;
    *(float4*)(out + (size_t)row * DIM + lane * 4) = o;
}

// ---------------- launcher ----------------
extern "C" void kernel_launch(void* const* d_in, const int* in_sizes, int n_in,
                              void* d_out, int out_size, void* d_ws, size_t ws_size,
                              hipStream_t stream) {
    const float* feats = (const float*)d_in[0];
    float* out = (float*)d_out;
    char* ws = (char*)d_ws;

    // ws: fb fp8 2MB | fbq fp8 2MB | fv fp8 2MB | Opart bf16 32MB | lpart fp32 256KB
    u8* fb = (u8*)ws;
    u8* fbq = (u8*)(ws + (size_t)BN * DIM);
    u8* fv = (u8*)(ws + (size_t)BN * DIM * 2);
    u16* Op = (u16*)(ws + (size_t)BN * DIM * 3);
    float* lp = (float*)(ws + (size_t)BN * DIM * 3 + (size_t)NSPLIT * BN * DIM * 2);

    k_prep<<<BN / 32, 256, 0, stream>>>(feats, fb, fbq, fv);
    k_flash<<<(BN / 128) * NSPLIT, 256, 0, stream>>>(fb, fbq, fv, Op, lp);
    k_combine<<<BN / 4, 256, 0, stream>>>(feats, Op, lp, out);
}

// Round 16
// 110.630 us; speedup vs baseline: 1.0150x; 1.0150x over previous
//
#include <hip/hip_runtime.h>

typedef unsigned char u8;
typedef unsigned short u16;
typedef unsigned int u32;
typedef unsigned long long u64;
typedef long long i64;
typedef __attribute__((ext_vector_type(16))) float floatx16;
typedef __attribute__((ext_vector_type(4))) int intx4;
typedef __attribute__((ext_vector_type(8))) int intx8;

#define BN 8192
#define DIM 256
#define NSPLIT 8
#define KPS (BN / NSPLIT)   // 1024 keys per split
#define BKN 64              // keys per barrier period (2 x 32-key QK subtiles)
#define NIT (KPS / BKN)     // 16 iters
#define L2E 1.44269504f     // log2(e)

__device__ __forceinline__ u16 f2bf(float x) {
    u32 u = __builtin_bit_cast(u32, x);
    u = (u + 0x7fffu + ((u >> 16) & 1u)) >> 16;
    return (u16)u;
}
__device__ __forceinline__ float bf2f(u16 h) {
    return __builtin_bit_cast(float, (u32)h << 16);
}
__device__ __forceinline__ u64 pack4bf(float a, float b, float c, float d) {
    return (u64)f2bf(a) | ((u64)f2bf(b) << 16) | ((u64)f2bf(c) << 32) | ((u64)f2bf(d) << 48);
}
__device__ __forceinline__ u32 pk_fp8(float a, float b, float c, float d) {
    int v = __builtin_amdgcn_cvt_pk_fp8_f32(a, b, 0, false);
    v = __builtin_amdgcn_cvt_pk_fp8_f32(c, d, v, true);
    return (u32)v;
}
__device__ __forceinline__ void gl_lds16(const void* g, void* l) {
    __builtin_amdgcn_global_load_lds(
        (const __attribute__((address_space(1))) u32*)g,
        (__attribute__((address_space(3))) u32*)l, 16, 0, 0);
}
// bare v_exp_f32 (2^x): R13 lesson — libm exp2f lowers to the OCML precise
// multi-instruction path (VALU ballooned 16->23us); the builtin is 1 instr.
__device__ __forceinline__ float ex2(float x) { return __builtin_amdgcn_exp2f(x); }
// v_permlane32_swap_b32 a, b: a' = [a.lo, b.lo], b' = [a.hi, b.hi]
__device__ __forceinline__ void plswap(u32& a, u32& b) {
    asm("v_permlane32_swap_b32 %0, %1" : "+v"(a), "+v"(b));
}
// MX-scaled fp8 MFMA, K=64, unit scales (e8m0 0x7F = 2^0): runs at the MX rate
// (4686 TF ubench = 2.13x the non-scaled fp8 rate). R18/R19 verified both sides.
#define MFMA64S(A, B, C) __builtin_amdgcn_mfma_scale_f32_32x32x64_f8f6f4( \
        (A), (B), (C), 0, 0, 0, (int)0x7f7f7f7f, 0, (int)0x7f7f7f7f)

// ---------------- kernel 1: row l2-norm -> fp8 fb (K image) + fbq (log2e-scaled Q image)
// + fp8 fv (V^T tile images) ----
__global__ __launch_bounds__(256) void k_prep(const float* __restrict__ in,
                                              u8* __restrict__ fb, u8* __restrict__ fbq,
                                              u8* __restrict__ fv) {
    __shared__ u16 t[32 * 260];
    const int tid = threadIdx.x;
    const int wave = tid >> 6, lane = tid & 63;
    const int kb = blockIdx.x, r0 = kb * 32;
    #pragma unroll
    for (int i = 0; i < 8; ++i) {
        const int rl = wave * 8 + i;
        const float4 v = *(const float4*)(in + (size_t)(r0 + rl) * DIM + lane * 4);
        float ss = v.x * v.x + v.y * v.y + v.z * v.z + v.w * v.w;
        #pragma unroll
        for (int off = 1; off < 64; off <<= 1) ss += __shfl_xor(ss, off, 64);
        const float inv = 1.0f / fmaxf(sqrtf(ss), 1e-12f);
        const float n0 = v.x * inv, n1 = v.y * inv, n2 = v.z * inv, n3 = v.w * inv;
        *(u32*)(fb + (size_t)(r0 + rl) * DIM + lane * 4) = pk_fp8(n0, n1, n2, n3);
        // Q image pre-scaled by log2e: exp(q.k) = 2^((L2E q).k) -> bare v_exp_f32 in flash
        *(u32*)(fbq + (size_t)(r0 + rl) * DIM + lane * 4) =
            pk_fp8(n0 * L2E, n1 * L2E, n2 * L2E, n3 * L2E);
        *(u64*)(&t[rl * 260 + lane * 4]) = pack4bf(n0, n1, n2, n3);
    }
    __syncthreads();
    #pragma unroll
    for (int i = 0; i < 4; ++i) {
        const int S = i * 256 + tid;              // 8-byte slot index 0..1023
        const int d = S >> 2;
        const int c = ((S & 3) - (d >> 2)) & 3;   // key octet
        float f[8];
        #pragma unroll
        for (int j = 0; j < 8; ++j) f[j] = bf2f(t[(8 * c + j) * 260 + d]);
        const u32 lo = pk_fp8(f[0], f[1], f[2], f[3]);
        const u32 hi = pk_fp8(f[4], f[5], f[6], f[7]);
        *(u64*)(fv + (size_t)kb * 8192 + S * 8) = ((u64)hi << 32) | lo;
    }
}

// ---------------- kernel 2: fp8 flash attention, K=64 MX path for QK AND PV ----------------
// R24 = R22 byte-for-byte (lock-in of the session best, 111.6us).
// R15 post-mortem: sleep 50 was neutral-to-negative (larger skew also delays
// the sleeping block's barrier-synced DMA staging chain) -> de-phase offset
// line CLOSED at sleep(24). Remaining in-kernel levers are closed by evidence
// (schedule perturbations R8, de-phase R15), structurally blocked (LDS 4-way
// floor under gl_lds16 linear-dest), or blocked by the 256-reg wall proven in
// R3/R13 (cross-seam pipelining needs +8-16 live regs).
// Budget: fill 46us (harness) + prep 2.5 + flash ~44 + combine ~9 (BW floor)
// + launch gaps ~10 = ~111.6.
__global__ __launch_bounds__(256, 2) void k_flash(
        const u8* __restrict__ fb, const u8* __restrict__ fbq, const u8* __restrict__ fv,
        u16* __restrict__ Opart, float* __restrict__ lpart) {
    __shared__ u8 tileK[2][16384];  // key-major fp8, chunk-swizzled, 2x32-key subtiles
    __shared__ u8 tileV[2][16384];  // pre-swizzled V^T fp8 images, 2x8KB subtiles

    const int tid = threadIdx.x;
    const int wave = tid >> 6, lane = tid & 63;
    const int c31 = lane & 31, g1 = lane >> 5;
    const int split = blockIdx.x & (NSPLIT - 1);
    const int qblk = blockIdx.x >> 3;
    const int q0 = qblk * 128 + wave * 32;
    const int key0 = split * KPS;

    // Q B-frags for K=64 MFMA (R18-verified layout), from the log2e-scaled image
    intx8 qf[4];
    #pragma unroll
    for (int g = 0; g < 4; ++g) {
        const u8* qb = fbq + (size_t)(q0 + c31) * DIM + g * 64 + g1 * 32;
        const intx4 lo = *(const intx4*)(qb);
        const intx4 hi = *(const intx4*)(qb + 16);
        qf[g] = __builtin_shufflevector(lo, hi, 0, 1, 2, 3, 4, 5, 6, 7);
    }

    floatx16 o[8];
    #pragma unroll
    for (int i = 0; i < 8; ++i)
        #pragma unroll
        for (int r = 0; r < 16; ++r) o[i][r] = 0.f;
    float lsum = 0.f;

    int offK[4];
    #pragma unroll
    for (int i = 0; i < 4; ++i) {
        const int S = wave * 256 + i * 64 + lane;   // 16B slot 0..1023 (64 key rows)
        const int r = S >> 4, s = S & 15;
        const int c = (s & 8) | ((s ^ r) & 7);
        offK[i] = r * 256 + c * 16;
    }
    const u8* gK = fb + (size_t)key0 * DIM;
    const u8* gV = fv + (size_t)(key0 >> 5) * 8192;

    auto stage = [&](int s, int b) {
        const size_t oo = (size_t)s * 16384;
        u8* lK = &tileK[b][0];
        u8* lV = &tileV[b][0] + wave * 4096;
        #pragma unroll
        for (int i = 0; i < 4; ++i)
            gl_lds16(gK + oo + offK[i], lK + wave * 4096 + i * 1024);
        #pragma unroll
        for (int i = 0; i < 4; ++i)
            gl_lds16(gV + oo + wave * 4096 + i * 1024 + lane * 16, lV + i * 1024);
    };

    // V chunk rotation offsets: piece p lives at chunk (p + (c31>>2)) & 3
    const int rot = c31 >> 2;
    const int co0 = ((rot) & 3) * 8, co1 = ((1 + rot) & 3) * 8;
    const int co2 = ((2 + rot) & 3) * 8, co3 = ((3 + rot) & 3) * 8;

    stage(0, 0);
    // de-phase the co-resident pair: bit 8 flips between block i and i+256
    if ((blockIdx.x >> 8) & 1) __builtin_amdgcn_s_sleep(24);   // ~1536 cyc, once

    for (int it = 0; it < NIT; ++it) {
        const int b = it & 1;
        __syncthreads();                   // drains DMA(it), issued one iter ago
        if (it + 1 < NIT) stage(it + 1, b ^ 1);

        const u8* tk = &tileK[b][0];
        const u8* bk0 = tk + c31 * 256;            // K subtile 0 (keys 0..31)
        const u8* bk1 = tk + 8192 + c31 * 256;     // K subtile 1 (keys 32..63)
        const u8* vbase = &tileV[b][0] + g1 * 8192 + c31 * 32;

        // K A-frag loader (R18-verified): k-group g from subtile base bk
        auto ldk = [&](const u8* bk, int g) -> intx8 {
            const int cw = g * 4 + g1 * 2;
            const int sl = (cw & 8) | ((cw ^ c31) & 7);
            const intx4 lo = *(const intx4*)(bk + sl * 16);
            const intx4 hi = *(const intx4*)(bk + (sl ^ 1) * 16);
            return __builtin_shufflevector(lo, hi, 0, 1, 2, 3, 4, 5, 6, 7);
        };
        // V B-frag loader: d-block ds, 4 rotated 8B pieces -> 8 u32 words
        auto ldv = [&](int ds) -> intx8 {
            const u8* vb = vbase + ds * 1024;
            const i64 v0 = *(const i64*)(vb + co0);
            const i64 v1 = *(const i64*)(vb + co1);
            const i64 v2 = *(const i64*)(vb + co2);
            const i64 v3 = *(const i64*)(vb + co3);
            intx8 r;
            r[0] = (int)v0; r[1] = (int)(v0 >> 32);
            r[2] = (int)v1; r[3] = (int)(v1 >> 32);
            r[4] = (int)v2; r[5] = (int)(v2 >> 32);
            r[6] = (int)v3; r[7] = (int)(v3 >> 32);
            return r;
        };

        floatx16 s0, s1;
        #pragma unroll
        for (int r = 0; r < 16; ++r) { s0[r] = 0.f; s1[r] = 0.f; }

        // ---- QK subtile 0 (keys 0..31), k-frag loads interleaved ----
        intx8 ka0 = ldk(bk0, 0);
        intx8 ka1 = ldk(bk0, 1);
        __builtin_amdgcn_s_setprio(1);
        s0 = MFMA64S(ka0, qf[0], s0); ka0 = ldk(bk0, 2);
        s0 = MFMA64S(ka1, qf[1], s0); ka1 = ldk(bk0, 3);
        s0 = MFMA64S(ka0, qf[2], s0); ka0 = ldk(bk1, 0);
        s0 = MFMA64S(ka1, qf[3], s0); ka1 = ldk(bk1, 1);
        __builtin_amdgcn_s_setprio(0);

        // ---- QK subtile 1 (keys 32..63), exp2(s0) interleaved ----
        __builtin_amdgcn_s_setprio(1);
        s1 = MFMA64S(ka0, qf[0], s1);
        const float f00 = ex2(s0[0]), f01 = ex2(s0[1]), f02 = ex2(s0[2]), f03 = ex2(s0[3]);
        const float f04 = ex2(s0[4]), f05 = ex2(s0[5]), f06 = ex2(s0[6]), f07 = ex2(s0[7]);
        ka0 = ldk(bk1, 2);
        s1 = MFMA64S(ka1, qf[1], s1);
        const float f08 = ex2(s0[8]), f09 = ex2(s0[9]), f10 = ex2(s0[10]), f11 = ex2(s0[11]);
        const float f12 = ex2(s0[12]), f13 = ex2(s0[13]), f14 = ex2(s0[14]), f15 = ex2(s0[15]);
        ka1 = ldk(bk1, 3);
        s1 = MFMA64S(ka0, qf[2], s1);
        const u32 pA0 = pk_fp8(f00, f01, f02, f03);
        const u32 pA1 = pk_fp8(f04, f05, f06, f07);
        const u32 pA2 = pk_fp8(f08, f09, f10, f11);
        const u32 pA3 = pk_fp8(f12, f13, f14, f15);
        lsum += ((f00 + f01) + (f02 + f03)) + ((f04 + f05) + (f06 + f07));
        lsum += ((f08 + f09) + (f10 + f11)) + ((f12 + f13) + (f14 + f15));
        s1 = MFMA64S(ka1, qf[3], s1);
        __builtin_amdgcn_s_setprio(0);

        // ---- exp2(s1) -> p(1); assemble K=64 P A-frag via permlane32_swap ----
        const float g00 = ex2(s1[0]), g01 = ex2(s1[1]), g02 = ex2(s1[2]), g03 = ex2(s1[3]);
        const float g04 = ex2(s1[4]), g05 = ex2(s1[5]), g06 = ex2(s1[6]), g07 = ex2(s1[7]);
        const float g08 = ex2(s1[8]), g09 = ex2(s1[9]), g10 = ex2(s1[10]), g11 = ex2(s1[11]);
        const float g12 = ex2(s1[12]), g13 = ex2(s1[13]), g14 = ex2(s1[14]), g15 = ex2(s1[15]);
        u32 w0 = pA0, w1 = pk_fp8(g00, g01, g02, g03);
        u32 w2 = pA1, w3 = pk_fp8(g04, g05, g06, g07);
        u32 w4 = pA2, w5 = pk_fp8(g08, g09, g10, g11);
        u32 w6 = pA3, w7 = pk_fp8(g12, g13, g14, g15);
        lsum += ((g00 + g01) + (g02 + g03)) + ((g04 + g05) + (g06 + g07));
        lsum += ((g08 + g09) + (g10 + g11)) + ((g12 + g13) + (g14 + g15));
        plswap(w0, w1);   // w0 = PA[0] = [pA.lo, pB.lo]; w1 = PA[1] = [pA.hi, pB.hi]
        plswap(w2, w3);
        plswap(w4, w5);
        plswap(w6, w7);
        intx8 PA;
        PA[0] = (int)w0; PA[1] = (int)w1;
        PA[2] = (int)w2; PA[3] = (int)w3;
        PA[4] = (int)w4; PA[5] = (int)w5;
        PA[6] = (int)w6; PA[7] = (int)w7;

        // ---- PV: 8 x K=64 MFMAs, V-frag loads pipelined 2 deep ----
        intx8 v0 = ldv(0), v1 = ldv(1);
        __builtin_amdgcn_s_setprio(1);
        o[0] = MFMA64S(PA, v0, o[0]); v0 = ldv(2);
        o[1] = MFMA64S(PA, v1, o[1]); v1 = ldv(3);
        o[2] = MFMA64S(PA, v0, o[2]); v0 = ldv(4);
        o[3] = MFMA64S(PA, v1, o[3]); v1 = ldv(5);
        o[4] = MFMA64S(PA, v0, o[4]); v0 = ldv(6);
        o[5] = MFMA64S(PA, v1, o[5]); v1 = ldv(7);
        o[6] = MFMA64S(PA, v0, o[6]);
        o[7] = MFMA64S(PA, v1, o[7]);
        __builtin_amdgcn_s_setprio(0);
    }

    // ---- epilogue: bf16 partial O + fp32 partial l ----
    u16* ob = Opart + ((size_t)split * BN + q0) * DIM;
    #pragma unroll
    for (int ds = 0; ds < 8; ++ds) {
        #pragma unroll
        for (int r = 0; r < 16; ++r) {
            const int ql = (r & 3) + 8 * (r >> 2) + 4 * g1;
            ob[(size_t)ql * DIM + ds * 32 + c31] = f2bf(o[ds][r]);
        }
    }
    lsum += __shfl_xor(lsum, 32, 64);
    if (g1 == 0) lpart[(size_t)split * BN + q0 + c31] = lsum;
}

// ---------------- kernel 3: merge splits, blend, final l2-normalize ----------------
__global__ __launch_bounds__(256) void k_combine(
        const float* __restrict__ feats, const u16* __restrict__ Opart,
        const float* __restrict__ lpart, float* __restrict__ out) {
    const int row = blockIdx.x * 4 + (threadIdx.x >> 6);
    const int lane = threadIdx.x & 63;

    float L = 0.f;
    #pragma unroll
    for (int s = 0; s < NSPLIT; ++s) L += lpart[(size_t)s * BN + row];

    float a0 = 0.f, a1 = 0.f, a2 = 0.f, a3 = 0.f;
    #pragma unroll
    for (int s = 0; s < NSPLIT; ++s) {
        const ushort4 o = *(const ushort4*)(Opart + ((size_t)s * BN + row) * DIM + lane * 4);
        a0 += bf2f(o.x); a1 += bf2f(o.y); a2 += bf2f(o.z); a3 += bf2f(o.w);
    }
    const float invL = 1.0f / L;

    const float4 v = *(const float4*)(feats + (size_t)row * DIM + lane * 4);
    float ss = v.x * v.x + v.y * v.y + v.z * v.z + v.w * v.w;
    #pragma unroll
    for (int off = 1; off < 64; off <<= 1) ss += __shfl_xor(ss, off, 64);
    const float invf = 1.0f / fmaxf(sqrtf(ss), 1e-12f);

    const float yx = 0.8f * v.x * invf + 0.2f * a0 * invL;
    const float yy = 0.8f * v.y * invf + 0.2f * a1 * invL;
    const float yz = 0.8f * v.z * invf + 0.2f * a2 * invL;
    const float yw = 0.8f * v.w * invf + 0.2f * a3 * invL;

    float s2 = yx * yx + yy * yy + yz * yz + yw * yw;
    #pragma unroll
    for (int off = 1; off < 64; off <<= 1) s2 += __shfl_xor(s2, off, 64);
    const float invn = 1.0f / fmaxf(sqrtf(s2), 1e-12f);

    float4 o; o.x = yx * invn; o.y = yy * invn; o.z = yz * invn; o.w = yw * invn;
    *(float4*)(out + (size_t)row * DIM + lane * 4) = o;
}

// ---------------- launcher ----------------
extern "C" void kernel_launch(void* const* d_in, const int* in_sizes, int n_in,
                              void* d_out, int out_size, void* d_ws, size_t ws_size,
                              hipStream_t stream) {
    const float* feats = (const float*)d_in[0];
    float* out = (float*)d_out;
    char* ws = (char*)d_ws;

    // ws: fb fp8 2MB | fbq fp8 2MB | fv fp8 2MB | Opart bf16 32MB | lpart fp32 256KB
    u8* fb = (u8*)ws;
    u8* fbq = (u8*)(ws + (size_t)BN * DIM);
    u8* fv = (u8*)(ws + (size_t)BN * DIM * 2);
    u16* Op = (u16*)(ws + (size_t)BN * DIM * 3);
    float* lp = (float*)(ws + (size_t)BN * DIM * 3 + (size_t)NSPLIT * BN * DIM * 2);

    k_prep<<<BN / 32, 256, 0, stream>>>(feats, fb, fbq, fv);
    k_flash<<<(BN / 128) * NSPLIT, 256, 0, stream>>>(fb, fbq, fv, Op, lp);
    k_combine<<<BN / 4, 256, 0, stream>>>(feats, Op, lp, out);
}